// Round 1
// baseline (354.784 us; speedup 1.0000x reference)
//
#include <hip/hip_runtime.h>
#include <hip/hip_bf16.h>
#include <stdint.h>

typedef unsigned short u16;
typedef __attribute__((ext_vector_type(4))) float f32x4;
typedef __attribute__((ext_vector_type(8))) short bf16x8;

#define GLL16(src, dst) __builtin_amdgcn_global_load_lds( \
    (const __attribute__((address_space(1))) void*)(src), \
    (__attribute__((address_space(3))) void*)(dst), 16, 0, 0)

static __device__ __forceinline__ u16 f2bf(float x) {
    uint32_t u = __builtin_bit_cast(uint32_t, x);
    u += 0x7fffu + ((u >> 16) & 1u);
    return (u16)(u >> 16);
}

// ---------------- fp32 -> bf16 conversion (vectorized) ----------------
__global__ __launch_bounds__(256) void cvt_f32_bf16(
        const float* __restrict__ in, u16* __restrict__ out, int n4) {
    int i = blockIdx.x * 256 + threadIdx.x;
    if (i >= n4) return;
    float4 v = ((const float4*)in)[i];
    ushort4 o;
    o.x = f2bf(v.x); o.y = f2bf(v.y); o.z = f2bf(v.z); o.w = f2bf(v.w);
    ((ushort4*)out)[i] = o;
}

// ---------------- GEMM: C[m,n] = sum_k A[m,k]*Bt[n,k] + bias[n] ----------------
// 128x128 tile, BK=32, 256 threads (4 waves 2x2, 64x64 each), mfma 16x16x32 bf16.
// LDS slot-swizzle: memslot = colchunk ^ ((row>>1)&3) both on stage-source and read.
// MODE 0: bf16 out row-major [M,N]
// MODE 1: bf16 out scattered to Vt[(b*16+h)*64+d][s]   (B=4,S=2048,NH=16,HD=64)
// MODE 2: fp32 out row-major [M,N]
template <int MODE>
__global__ __launch_bounds__(256, 2) void gemm_bt(
        const u16* __restrict__ A, const u16* __restrict__ Bt,
        const float* __restrict__ bias, void* __restrict__ outp,
        int M, int N, int K) {
    __shared__ __align__(16) u16 As[128 * 32];
    __shared__ __align__(16) u16 Bs[128 * 32];
    const int tid = threadIdx.x;
    const int lane = tid & 63;
    const int w = tid >> 6, wm = w >> 1, wn = w & 1;
    const int l15 = lane & 15, l4 = lane >> 4;
    const int m0 = blockIdx.y * 128, n0 = blockIdx.x * 128;

    f32x4 acc[4][4];
#pragma unroll
    for (int i = 0; i < 4; i++)
#pragma unroll
        for (int j = 0; j < 4; j++) acc[i][j] = f32x4{0.f, 0.f, 0.f, 0.f};

    for (int kt = 0; kt < K; kt += 32) {
        __syncthreads();
        // stage A tile [128 rows][32 cols] : 512 x 16B chunks, 2 per thread
#pragma unroll
        for (int i = 0; i < 2; i++) {
            int c = tid + i * 256;
            int row = c >> 2, slot = c & 3;
            int cc = slot ^ ((row >> 1) & 3);   // pre-swizzled source chunk
            GLL16(A + (size_t)(m0 + row) * K + kt + cc * 8, As + c * 8);
        }
#pragma unroll
        for (int i = 0; i < 2; i++) {
            int c = tid + i * 256;
            int row = c >> 2, slot = c & 3;
            int cc = slot ^ ((row >> 1) & 3);
            GLL16(Bt + (size_t)(n0 + row) * K + kt + cc * 8, Bs + c * 8);
        }
        __syncthreads();

        bf16x8 af[4], bfr[4];
#pragma unroll
        for (int i = 0; i < 4; i++) {
            int row = wm * 64 + i * 16 + l15;
            int slot = l4 ^ ((row >> 1) & 3);
            af[i] = *(const bf16x8*)(As + row * 32 + slot * 8);
        }
#pragma unroll
        for (int j = 0; j < 4; j++) {
            int row = wn * 64 + j * 16 + l15;
            int slot = l4 ^ ((row >> 1) & 3);
            bfr[j] = *(const bf16x8*)(Bs + row * 32 + slot * 8);
        }
#pragma unroll
        for (int i = 0; i < 4; i++)
#pragma unroll
            for (int j = 0; j < 4; j++)
                acc[i][j] = __builtin_amdgcn_mfma_f32_16x16x32_bf16(af[i], bfr[j], acc[i][j], 0, 0, 0);
    }

    // epilogue: C row = m0+wm*64+i*16+l4*4+r, col = n0+wn*64+j*16+l15
#pragma unroll
    for (int j = 0; j < 4; j++) {
        int col = n0 + wn * 64 + j * 16 + l15;
        float bv = bias[col];
#pragma unroll
        for (int i = 0; i < 4; i++) {
            int rowb = m0 + wm * 64 + i * 16 + l4 * 4;
            if (MODE == 0) {
                u16* out = (u16*)outp;
#pragma unroll
                for (int r = 0; r < 4; r++)
                    out[(size_t)(rowb + r) * N + col] = f2bf(acc[i][j][r] + bv);
            } else if (MODE == 1) {
                u16* out = (u16*)outp;
                int bb = rowb >> 11, s = rowb & 2047;
                int hh = col >> 6, dd = col & 63;
                ushort4 o;
                o.x = f2bf(acc[i][j][0] + bv);
                o.y = f2bf(acc[i][j][1] + bv);
                o.z = f2bf(acc[i][j][2] + bv);
                o.w = f2bf(acc[i][j][3] + bv);
                *(ushort4*)(out + ((size_t)((bb * 16 + hh) * 64 + dd)) * 2048 + s) = o;
            } else {
                float* out = (float*)outp;
#pragma unroll
                for (int r = 0; r < 4; r++)
                    out[(size_t)(rowb + r) * N + col] = acc[i][j][r] + bv;
            }
        }
    }
}

// ---------------- fused flash attention ----------------
// grid (S/128, B*NH). 256 threads = 4 waves, each wave owns 32 q-rows.
// Q,K: [8192,1024] bf16 (token-major), Vt: [(b*16+h)][d][s] bf16.
// scores = QK^T/32, mask(-1e12), online softmax, ctx -> [8192,1024] bf16.
__global__ __launch_bounds__(256, 2) void attn_fused(
        const u16* __restrict__ Q, const u16* __restrict__ K,
        const u16* __restrict__ Vt, const float* __restrict__ mask,
        u16* __restrict__ ctx) {
    __shared__ __align__(16) u16 Ks[64 * 64];       // [kv][d], swizzled
    __shared__ __align__(16) u16 Vs[64 * 64];       // [d][kv], swizzled
    __shared__ __align__(16) u16 Ps[4][32 * 64];    // per-wave P [q][kv], swizzled

    const int tid = threadIdx.x, lane = tid & 63, w = tid >> 6;
    const int l15 = lane & 15, l4 = lane >> 4;
    const int bh = blockIdx.y, b = bh >> 4, h = bh & 15;
    const int qw = blockIdx.x * 128 + w * 32;       // wave's q base within sequence

    const u16* Qg = Q + (size_t)b * 2048 * 1024 + h * 64;
    const u16* Kg = K + (size_t)b * 2048 * 1024 + h * 64;
    const u16* Vg = Vt + (size_t)bh * 64 * 2048;
    const float* mp = mask + b * 2048;

    // hoist Q fragments: A-layout, lane holds Q[qw+mi*16+l15][kf*32+l4*8 + 0..7]
    bf16x8 qf[2][2];
#pragma unroll
    for (int mi = 0; mi < 2; mi++)
#pragma unroll
        for (int kf = 0; kf < 2; kf++)
            qf[mi][kf] = *(const bf16x8*)(Qg + (size_t)(qw + mi * 16 + l15) * 1024 + kf * 32 + l4 * 8);

    // query-row masks for the C-layout rows this lane owns
    float mq[2][4];
#pragma unroll
    for (int mi = 0; mi < 2; mi++)
#pragma unroll
        for (int r = 0; r < 4; r++)
            mq[mi][r] = mp[qw + mi * 16 + l4 * 4 + r];

    float m_run[2][4], l_run[2][4];
    f32x4 oacc[2][4];
#pragma unroll
    for (int mi = 0; mi < 2; mi++)
#pragma unroll
        for (int r = 0; r < 4; r++) { m_run[mi][r] = -__builtin_inff(); l_run[mi][r] = 0.f; }
#pragma unroll
    for (int mi = 0; mi < 2; mi++)
#pragma unroll
        for (int nf = 0; nf < 4; nf++) oacc[mi][nf] = f32x4{0.f, 0.f, 0.f, 0.f};

    for (int kv0 = 0; kv0 < 2048; kv0 += 64) {
        __syncthreads();
        // stage K tile [64 kv][64 d] and Vt tile [64 d][64 kv]; 512 chunks each
#pragma unroll
        for (int i = 0; i < 2; i++) {
            int c = tid + i * 256;
            int row = c >> 3, slot = c & 7;
            int cc = slot ^ (row & 7);
            GLL16(Kg + (size_t)(kv0 + row) * 1024 + cc * 8, Ks + c * 8);
        }
#pragma unroll
        for (int i = 0; i < 2; i++) {
            int c = tid + i * 256;
            int row = c >> 3, slot = c & 7;
            int cc = slot ^ (row & 7);
            GLL16(Vg + (size_t)row * 2048 + kv0 + cc * 8, Vs + c * 8);
        }
        __syncthreads();

        // ---- QK^T : p[mi][nf] over 32 q x 64 kv ----
        bf16x8 kfr[4][2];
#pragma unroll
        for (int nf = 0; nf < 4; nf++)
#pragma unroll
            for (int kf = 0; kf < 2; kf++) {
                int row = nf * 16 + l15;
                int slot = (kf * 4 + l4) ^ (row & 7);
                kfr[nf][kf] = *(const bf16x8*)(Ks + row * 64 + slot * 8);
            }
        f32x4 p[2][4];
#pragma unroll
        for (int mi = 0; mi < 2; mi++)
#pragma unroll
            for (int nf = 0; nf < 4; nf++) p[mi][nf] = f32x4{0.f, 0.f, 0.f, 0.f};
#pragma unroll
        for (int mi = 0; mi < 2; mi++)
#pragma unroll
            for (int nf = 0; nf < 4; nf++)
#pragma unroll
                for (int kf = 0; kf < 2; kf++)
                    p[mi][nf] = __builtin_amdgcn_mfma_f32_16x16x32_bf16(qf[mi][kf], kfr[nf][kf], p[mi][nf], 0, 0, 0);

        // key masks for the 4 cols this lane sees
        float mk[4];
#pragma unroll
        for (int nf = 0; nf < 4; nf++) mk[nf] = mp[kv0 + nf * 16 + l15];

        // ---- online softmax (wave-parallel, 16-lane row groups) ----
#pragma unroll
        for (int mi = 0; mi < 2; mi++)
#pragma unroll
            for (int r = 0; r < 4; r++) {
                float pm = -__builtin_inff();
#pragma unroll
                for (int nf = 0; nf < 4; nf++) {
                    float s = p[mi][nf][r] * 0.03125f;   // /sqrt(1024)
                    s = (mq[mi][r] != 0.f && mk[nf] != 0.f) ? s : -1e12f;
                    p[mi][nf][r] = s;
                    pm = fmaxf(pm, s);
                }
                for (int d = 1; d < 16; d <<= 1) pm = fmaxf(pm, __shfl_xor(pm, d));
                float mn = fmaxf(m_run[mi][r], pm);
                float sc = __expf(m_run[mi][r] - mn);
                m_run[mi][r] = mn;
                float rs = 0.f;
#pragma unroll
                for (int nf = 0; nf < 4; nf++) {
                    float ev = __expf(p[mi][nf][r] - mn);
                    p[mi][nf][r] = ev;
                    rs += ev;
                }
                for (int d = 1; d < 16; d <<= 1) rs += __shfl_xor(rs, d);
                l_run[mi][r] = l_run[mi][r] * sc + rs;
#pragma unroll
                for (int nf = 0; nf < 4; nf++) oacc[mi][nf][r] *= sc;
            }

        // ---- write P (D-layout) into swizzled wave-private LDS ----
#pragma unroll
        for (int mi = 0; mi < 2; mi++)
#pragma unroll
            for (int nf = 0; nf < 4; nf++)
#pragma unroll
                for (int r = 0; r < 4; r++) {
                    int prow = mi * 16 + l4 * 4 + r;
                    int pcol = nf * 16 + l15;
                    Ps[w][prow * 64 + (((pcol >> 3) ^ (prow & 7)) << 3) + (pcol & 7)] = f2bf(p[mi][nf][r]);
                }

        // ---- PV : oacc[mi][nf(d)] += P[32,64] @ V[64,64] ----
        bf16x8 vfr[4][2], pa[2][2];
#pragma unroll
        for (int nf = 0; nf < 4; nf++)
#pragma unroll
            for (int kf = 0; kf < 2; kf++) {
                int row = nf * 16 + l15;
                int slot = (kf * 4 + l4) ^ (row & 7);
                vfr[nf][kf] = *(const bf16x8*)(Vs + row * 64 + slot * 8);
            }
#pragma unroll
        for (int mi = 0; mi < 2; mi++)
#pragma unroll
            for (int kf = 0; kf < 2; kf++) {
                int row = mi * 16 + l15;
                int slot = (kf * 4 + l4) ^ (row & 7);
                pa[mi][kf] = *(const bf16x8*)(Ps[w] + row * 64 + slot * 8);
            }
#pragma unroll
        for (int mi = 0; mi < 2; mi++)
#pragma unroll
            for (int nf = 0; nf < 4; nf++)
#pragma unroll
                for (int kf = 0; kf < 2; kf++)
                    oacc[mi][nf] = __builtin_amdgcn_mfma_f32_16x16x32_bf16(pa[mi][kf], vfr[nf][kf], oacc[mi][nf], 0, 0, 0);
    }

    // ---- epilogue: ctx = oacc / l_run ----
#pragma unroll
    for (int mi = 0; mi < 2; mi++)
#pragma unroll
        for (int nf = 0; nf < 4; nf++) {
            int col = h * 64 + nf * 16 + l15;
#pragma unroll
            for (int r = 0; r < 4; r++) {
                int row = qw + mi * 16 + l4 * 4 + r;
                float v = oacc[mi][nf][r] / l_run[mi][r];
                ctx[(size_t)(b * 2048 + row) * 1024 + col] = f2bf(v);
            }
        }
}

extern "C" void kernel_launch(void* const* d_in, const int* in_sizes, int n_in,
                              void* d_out, int out_size, void* d_ws, size_t ws_size,
                              hipStream_t stream) {
    const float* hs    = (const float*)d_in[0];
    const float* masks = (const float*)d_in[1];
    const float* Wq = (const float*)d_in[2];
    const float* bq = (const float*)d_in[3];
    const float* Wk = (const float*)d_in[4];
    const float* bk = (const float*)d_in[5];
    const float* Wv = (const float*)d_in[6];
    const float* bv = (const float*)d_in[7];
    const float* Wo = (const float*)d_in[8];
    const float* bo = (const float*)d_in[9];

    const int NT = 4 * 2048;   // 8192 tokens
    const int H = 1024;

    u16* hs_b = (u16*)d_ws;                       // [8192,1024] bf16 hidden (reused as ctx)
    u16* wq_b = hs_b + (size_t)NT * H;
    u16* wk_b = wq_b + (size_t)H * H;
    u16* wv_b = wk_b + (size_t)H * H;
    u16* wo_b = wv_b + (size_t)H * H;
    u16* Qb   = wo_b + (size_t)H * H;             // [8192,1024]
    u16* Kb   = Qb + (size_t)NT * H;              // [8192,1024]
    u16* Vtb  = Kb + (size_t)NT * H;              // [64][64][2048]
    u16* Cb   = hs_b;                             // attention output reuses hidden buffer

    cvt_f32_bf16<<<NT * H / 1024, 256, 0, stream>>>(hs, hs_b, NT * H / 4);
    cvt_f32_bf16<<<H * H / 1024, 256, 0, stream>>>(Wq, wq_b, H * H / 4);
    cvt_f32_bf16<<<H * H / 1024, 256, 0, stream>>>(Wk, wk_b, H * H / 4);
    cvt_f32_bf16<<<H * H / 1024, 256, 0, stream>>>(Wv, wv_b, H * H / 4);
    cvt_f32_bf16<<<H * H / 1024, 256, 0, stream>>>(Wo, wo_b, H * H / 4);

    dim3 gg(H / 128, NT / 128);   // (8, 64)
    gemm_bt<0><<<gg, 256, 0, stream>>>(hs_b, wq_b, bq, Qb,  NT, H, H);
    gemm_bt<0><<<gg, 256, 0, stream>>>(hs_b, wk_b, bk, Kb,  NT, H, H);
    gemm_bt<1><<<gg, 256, 0, stream>>>(hs_b, wv_b, bv, Vtb, NT, H, H);

    attn_fused<<<dim3(2048 / 128, 64), 256, 0, stream>>>(Qb, Kb, Vtb, masks, Cb);

    gemm_bt<2><<<gg, 256, 0, stream>>>(Cb, wo_b, bo, d_out, NT, H, H);
}

// Round 2
// 284.585 us; speedup vs baseline: 1.2467x; 1.2467x over previous
//
#include <hip/hip_runtime.h>
#include <hip/hip_bf16.h>
#include <stdint.h>

typedef unsigned short u16;
typedef __attribute__((ext_vector_type(4))) float f32x4;
typedef __attribute__((ext_vector_type(8))) short bf16x8;

#define GLL16(src, dst) __builtin_amdgcn_global_load_lds( \
    (const __attribute__((address_space(1))) void*)(src), \
    (__attribute__((address_space(3))) void*)(dst), 16, 0, 0)

static __device__ __forceinline__ u16 f2bf(float x) {
    uint32_t u = __builtin_bit_cast(uint32_t, x);
    u += 0x7fffu + ((u >> 16) & 1u);
    return (u16)(u >> 16);
}

// ---------------- fp32 -> bf16 conversion (vectorized) ----------------
__global__ __launch_bounds__(256) void cvt_f32_bf16(
        const float* __restrict__ in, u16* __restrict__ out, int n4) {
    int i = blockIdx.x * 256 + threadIdx.x;
    if (i >= n4) return;
    float4 v = ((const float4*)in)[i];
    ushort4 o;
    o.x = f2bf(v.x); o.y = f2bf(v.y); o.z = f2bf(v.z); o.w = f2bf(v.w);
    ((ushort4*)out)[i] = o;
}

// ---------------- GEMM: C[m,n] = sum_k A[m,k]*Bt[n,k] + bias[n] ----------------
// 128x128 tile, BK=32, 256 threads (4 waves 2x2, 64x64 each), mfma 16x16x32 bf16.
// MODE 0: bf16 out row-major [M,N]
// MODE 1: bf16 out scattered to Vt[(b*16+h)*64+d][s]
// MODE 2: fp32 out row-major [M,N]
template <int MODE>
__global__ __launch_bounds__(256, 2) void gemm_bt(
        const u16* __restrict__ A, const u16* __restrict__ Bt,
        const float* __restrict__ bias, void* __restrict__ outp,
        int M, int N, int K) {
    __shared__ __align__(16) u16 As[128 * 32];
    __shared__ __align__(16) u16 Bs[128 * 32];
    const int tid = threadIdx.x;
    const int lane = tid & 63;
    const int w = tid >> 6, wm = w >> 1, wn = w & 1;
    const int l15 = lane & 15, l4 = lane >> 4;
    const int m0 = blockIdx.y * 128, n0 = blockIdx.x * 128;

    f32x4 acc[4][4];
#pragma unroll
    for (int i = 0; i < 4; i++)
#pragma unroll
        for (int j = 0; j < 4; j++) acc[i][j] = f32x4{0.f, 0.f, 0.f, 0.f};

    for (int kt = 0; kt < K; kt += 32) {
        __syncthreads();
#pragma unroll
        for (int i = 0; i < 2; i++) {
            int c = tid + i * 256;
            int row = c >> 2, slot = c & 3;
            int cc = slot ^ ((row >> 1) & 3);
            GLL16(A + (size_t)(m0 + row) * K + kt + cc * 8, As + c * 8);
        }
#pragma unroll
        for (int i = 0; i < 2; i++) {
            int c = tid + i * 256;
            int row = c >> 2, slot = c & 3;
            int cc = slot ^ ((row >> 1) & 3);
            GLL16(Bt + (size_t)(n0 + row) * K + kt + cc * 8, Bs + c * 8);
        }
        __syncthreads();

        bf16x8 af[4], bfr[4];
#pragma unroll
        for (int i = 0; i < 4; i++) {
            int row = wm * 64 + i * 16 + l15;
            int slot = l4 ^ ((row >> 1) & 3);
            af[i] = *(const bf16x8*)(As + row * 32 + slot * 8);
        }
#pragma unroll
        for (int j = 0; j < 4; j++) {
            int row = wn * 64 + j * 16 + l15;
            int slot = l4 ^ ((row >> 1) & 3);
            bfr[j] = *(const bf16x8*)(Bs + row * 32 + slot * 8);
        }
#pragma unroll
        for (int i = 0; i < 4; i++)
#pragma unroll
            for (int j = 0; j < 4; j++)
                acc[i][j] = __builtin_amdgcn_mfma_f32_16x16x32_bf16(af[i], bfr[j], acc[i][j], 0, 0, 0);
    }

#pragma unroll
    for (int j = 0; j < 4; j++) {
        int col = n0 + wn * 64 + j * 16 + l15;
        float bv = bias[col];
#pragma unroll
        for (int i = 0; i < 4; i++) {
            int rowb = m0 + wm * 64 + i * 16 + l4 * 4;
            if (MODE == 0) {
                u16* out = (u16*)outp;
#pragma unroll
                for (int r = 0; r < 4; r++)
                    out[(size_t)(rowb + r) * N + col] = f2bf(acc[i][j][r] + bv);
            } else if (MODE == 1) {
                u16* out = (u16*)outp;
                int bb = rowb >> 11, s = rowb & 2047;
                int hh = col >> 6, dd = col & 63;
                ushort4 o;
                o.x = f2bf(acc[i][j][0] + bv);
                o.y = f2bf(acc[i][j][1] + bv);
                o.z = f2bf(acc[i][j][2] + bv);
                o.w = f2bf(acc[i][j][3] + bv);
                *(ushort4*)(out + ((size_t)((bb * 16 + hh) * 64 + dd)) * 2048 + s) = o;
            } else {
                float* out = (float*)outp;
#pragma unroll
                for (int r = 0; r < 4; r++)
                    out[(size_t)(rowb + r) * N + col] = acc[i][j][r] + bv;
            }
        }
    }
}

// ---------------- fused flash attention (swapped-operand / transposed) ----------------
// grid (S/128, B*NH). 256 threads = 4 waves, each wave owns 32 q-rows.
// S^T = mfma(K_frag, Q_frag): lane holds one q-col (q=l15), kv rows in regs ->
// softmax row-reduce is in-lane + 2 shuffles. O^T = mfma(Vt_frag, P^T_frag):
// rescale is lane-local; epilogue stores ushort4 runs of d.
__global__ __launch_bounds__(256, 4) void attn_fused(
        const u16* __restrict__ Q, const u16* __restrict__ K,
        const u16* __restrict__ Vt, const float* __restrict__ mask,
        u16* __restrict__ ctx) {
    __shared__ __align__(16) u16 Ks[64 * 64];       // [kv][d], swizzled
    __shared__ __align__(16) u16 Vs[64 * 64];       // [d][kv], swizzled
    __shared__ __align__(16) u16 Ps[4][32 * 64];    // per-wave P^T as [q][kv], swizzled

    const int tid = threadIdx.x, lane = tid & 63, w = tid >> 6;
    const int l15 = lane & 15, l4 = lane >> 4;
    const int bh = blockIdx.y, b = bh >> 4, h = bh & 15;
    const int qw = blockIdx.x * 128 + w * 32;

    const u16* Qg = Q + (size_t)b * 2048 * 1024 + h * 64;
    const u16* Kg = K + (size_t)b * 2048 * 1024 + h * 64;
    const u16* Vg = Vt + (size_t)bh * 64 * 2048;
    const float* mp = mask + b * 2048;

    // hoist Q fragments (B-operand layout): lane holds Q[qw+qi*16+l15][kf*32+l4*8+0..7]
    bf16x8 qfr[2][2];
#pragma unroll
    for (int qi = 0; qi < 2; qi++)
#pragma unroll
        for (int kf = 0; kf < 2; kf++)
            qfr[qi][kf] = *(const bf16x8*)(Qg + (size_t)(qw + qi * 16 + l15) * 1024 + kf * 32 + l4 * 8);

    // per-lane query mask (q = l15 within each qi group)
    float mqv[2];
#pragma unroll
    for (int qi = 0; qi < 2; qi++) mqv[qi] = mp[qw + qi * 16 + l15];

    float m_run[2], l_run[2];
    f32x4 oaccT[4][2];   // O^T: [d-frag][q-frag], row=d=l4*4+reg, col=q=l15
#pragma unroll
    for (int qi = 0; qi < 2; qi++) { m_run[qi] = -__builtin_inff(); l_run[qi] = 0.f; }
#pragma unroll
    for (int df = 0; df < 4; df++)
#pragma unroll
        for (int qi = 0; qi < 2; qi++) oaccT[df][qi] = f32x4{0.f, 0.f, 0.f, 0.f};

    for (int kv0 = 0; kv0 < 2048; kv0 += 64) {
        __syncthreads();
#pragma unroll
        for (int i = 0; i < 2; i++) {
            int c = tid + i * 256;
            int row = c >> 3, slot = c & 7;
            int cc = slot ^ (row & 7);
            GLL16(Kg + (size_t)(kv0 + row) * 1024 + cc * 8, Ks + c * 8);
        }
#pragma unroll
        for (int i = 0; i < 2; i++) {
            int c = tid + i * 256;
            int row = c >> 3, slot = c & 7;
            int cc = slot ^ (row & 7);
            GLL16(Vg + (size_t)row * 2048 + kv0 + cc * 8, Vs + c * 8);
        }
        __syncthreads();

        // ---- S^T = K Q^T : p[kvf][qi], row=kv=l4*4+reg, col=q=l15 ----
        bf16x8 kfr[4][2];
#pragma unroll
        for (int kvf = 0; kvf < 4; kvf++)
#pragma unroll
            for (int kf = 0; kf < 2; kf++) {
                int row = kvf * 16 + l15;
                int slot = (kf * 4 + l4) ^ (row & 7);
                kfr[kvf][kf] = *(const bf16x8*)(Ks + row * 64 + slot * 8);
            }
        f32x4 p[4][2];
#pragma unroll
        for (int kvf = 0; kvf < 4; kvf++)
#pragma unroll
            for (int qi = 0; qi < 2; qi++) p[kvf][qi] = f32x4{0.f, 0.f, 0.f, 0.f};
#pragma unroll
        for (int kvf = 0; kvf < 4; kvf++)
#pragma unroll
            for (int qi = 0; qi < 2; qi++)
#pragma unroll
                for (int kf = 0; kf < 2; kf++)
                    p[kvf][qi] = __builtin_amdgcn_mfma_f32_16x16x32_bf16(kfr[kvf][kf], qfr[qi][kf], p[kvf][qi], 0, 0, 0);

        // key-side mask, 4 values per lane per kvf (kv = kvf*16 + l4*4 + r)
        float4 mkv[4];
#pragma unroll
        for (int kvf = 0; kvf < 4; kvf++)
            mkv[kvf] = ((const float4*)(mp + kv0))[kvf * 4 + l4];

        // ---- online softmax: in-lane over 16 kv + 2 shuffles across the 4-lane group ----
#pragma unroll
        for (int qi = 0; qi < 2; qi++) {
            float pm = -__builtin_inff();
#pragma unroll
            for (int kvf = 0; kvf < 4; kvf++)
#pragma unroll
                for (int r = 0; r < 4; r++) {
                    float s = (mqv[qi] != 0.f && mkv[kvf][r] != 0.f)
                                  ? p[kvf][qi][r] * 0.03125f : -1e12f;
                    p[kvf][qi][r] = s;
                    pm = fmaxf(pm, s);
                }
            pm = fmaxf(pm, __shfl_xor(pm, 16));
            pm = fmaxf(pm, __shfl_xor(pm, 32));
            float mn = fmaxf(m_run[qi], pm);
            float sc = __expf(m_run[qi] - mn);
            m_run[qi] = mn;
            float rs = 0.f;
#pragma unroll
            for (int kvf = 0; kvf < 4; kvf++)
#pragma unroll
                for (int r = 0; r < 4; r++) {
                    float ev = __expf(p[kvf][qi][r] - mn);
                    p[kvf][qi][r] = ev;
                    rs += ev;
                }
            rs += __shfl_xor(rs, 16);
            rs += __shfl_xor(rs, 32);
            l_run[qi] = l_run[qi] * sc + rs;
#pragma unroll
            for (int df = 0; df < 4; df++) oaccT[df][qi] *= sc;
        }

        // ---- P^T -> LDS [q=32][kv=64] (packed b64 writes, 16B-slot XOR swizzle) ----
#pragma unroll
        for (int qi = 0; qi < 2; qi++)
#pragma unroll
            for (int kvf = 0; kvf < 4; kvf++) {
                int q = qi * 16 + l15;
                uint32_t lo = (uint32_t)f2bf(p[kvf][qi][0]) | ((uint32_t)f2bf(p[kvf][qi][1]) << 16);
                uint32_t hi = (uint32_t)f2bf(p[kvf][qi][2]) | ((uint32_t)f2bf(p[kvf][qi][3]) << 16);
                int s8 = kvf * 2 + (l4 >> 1);
                int off = q * 64 + ((s8 ^ (q & 7)) << 3) + (l4 & 1) * 4;
                *(uint2*)(Ps[w] + off) = uint2{lo, hi};
            }

        // ---- O^T += V^T P^T : A=Vt frag (d rows), B=P^T frag (q cols) ----
        bf16x8 vfr[4][2], pb[2][2];
#pragma unroll
        for (int df = 0; df < 4; df++)
#pragma unroll
            for (int kf = 0; kf < 2; kf++) {
                int row = df * 16 + l15;
                int slot = (kf * 4 + l4) ^ (row & 7);
                vfr[df][kf] = *(const bf16x8*)(Vs + row * 64 + slot * 8);
            }
#pragma unroll
        for (int qi = 0; qi < 2; qi++)
#pragma unroll
            for (int kf = 0; kf < 2; kf++) {
                int q = qi * 16 + l15;
                int s8 = kf * 4 + l4;
                pb[qi][kf] = *(const bf16x8*)(Ps[w] + q * 64 + ((s8 ^ (q & 7)) << 3));
            }
#pragma unroll
        for (int df = 0; df < 4; df++)
#pragma unroll
            for (int qi = 0; qi < 2; qi++)
#pragma unroll
                for (int kf = 0; kf < 2; kf++)
                    oaccT[df][qi] = __builtin_amdgcn_mfma_f32_16x16x32_bf16(vfr[df][kf], pb[qi][kf], oaccT[df][qi], 0, 0, 0);
    }

    // ---- epilogue: ctx[token][h*64+d] = O^T / l, contiguous 4-d ushort4 stores ----
#pragma unroll
    for (int qi = 0; qi < 2; qi++) {
        float rl = 1.0f / l_run[qi];
        int tok = qw + qi * 16 + l15;
#pragma unroll
        for (int df = 0; df < 4; df++) {
            ushort4 o;
            o.x = f2bf(oaccT[df][qi][0] * rl);
            o.y = f2bf(oaccT[df][qi][1] * rl);
            o.z = f2bf(oaccT[df][qi][2] * rl);
            o.w = f2bf(oaccT[df][qi][3] * rl);
            *(ushort4*)(ctx + (size_t)(b * 2048 + tok) * 1024 + h * 64 + df * 16 + l4 * 4) = o;
        }
    }
}

extern "C" void kernel_launch(void* const* d_in, const int* in_sizes, int n_in,
                              void* d_out, int out_size, void* d_ws, size_t ws_size,
                              hipStream_t stream) {
    const float* hs    = (const float*)d_in[0];
    const float* masks = (const float*)d_in[1];
    const float* Wq = (const float*)d_in[2];
    const float* bq = (const float*)d_in[3];
    const float* Wk = (const float*)d_in[4];
    const float* bk = (const float*)d_in[5];
    const float* Wv = (const float*)d_in[6];
    const float* bv = (const float*)d_in[7];
    const float* Wo = (const float*)d_in[8];
    const float* bo = (const float*)d_in[9];

    const int NT = 4 * 2048;   // 8192 tokens
    const int H = 1024;

    u16* hs_b = (u16*)d_ws;
    u16* wq_b = hs_b + (size_t)NT * H;
    u16* wk_b = wq_b + (size_t)H * H;
    u16* wv_b = wk_b + (size_t)H * H;
    u16* wo_b = wv_b + (size_t)H * H;
    u16* Qb   = wo_b + (size_t)H * H;
    u16* Kb   = Qb + (size_t)NT * H;
    u16* Vtb  = Kb + (size_t)NT * H;
    u16* Cb   = hs_b;

    cvt_f32_bf16<<<NT * H / 1024, 256, 0, stream>>>(hs, hs_b, NT * H / 4);
    cvt_f32_bf16<<<H * H / 1024, 256, 0, stream>>>(Wq, wq_b, H * H / 4);
    cvt_f32_bf16<<<H * H / 1024, 256, 0, stream>>>(Wk, wk_b, H * H / 4);
    cvt_f32_bf16<<<H * H / 1024, 256, 0, stream>>>(Wv, wv_b, H * H / 4);
    cvt_f32_bf16<<<H * H / 1024, 256, 0, stream>>>(Wo, wo_b, H * H / 4);

    dim3 gg(H / 128, NT / 128);   // (8, 64)
    gemm_bt<0><<<gg, 256, 0, stream>>>(hs_b, wq_b, bq, Qb,  NT, H, H);
    gemm_bt<0><<<gg, 256, 0, stream>>>(hs_b, wk_b, bk, Kb,  NT, H, H);
    gemm_bt<1><<<gg, 256, 0, stream>>>(hs_b, wv_b, bv, Vtb, NT, H, H);

    attn_fused<<<dim3(2048 / 128, 64), 256, 0, stream>>>(Qb, Kb, Vtb, masks, Cb);

    gemm_bt<2><<<gg, 256, 0, stream>>>(Cb, wo_b, bo, d_out, NT, H, H);
}

// Round 3
// 262.810 us; speedup vs baseline: 1.3500x; 1.0829x over previous
//
#include <hip/hip_runtime.h>
#include <hip/hip_bf16.h>
#include <stdint.h>

typedef unsigned short u16;
typedef __attribute__((ext_vector_type(4))) float f32x4;
typedef __attribute__((ext_vector_type(8))) short bf16x8;

#define GLL16(src, dst) __builtin_amdgcn_global_load_lds( \
    (const __attribute__((address_space(1))) void*)(src), \
    (__attribute__((address_space(3))) void*)(dst), 16, 0, 0)

static __device__ __forceinline__ u16 f2bf(float x) {
    uint32_t u = __builtin_bit_cast(uint32_t, x);
    u += 0x7fffu + ((u >> 16) & 1u);
    return (u16)(u >> 16);
}

static __device__ __forceinline__ uint32_t cvtpk(float lo, float hi) {
    uint32_t r;
    asm("v_cvt_pk_bf16_f32 %0, %1, %2" : "=v"(r) : "v"(lo), "v"(hi));
    return r;
}

// ---------------- fp32 -> bf16 conversion (vectorized) ----------------
__global__ __launch_bounds__(256) void cvt_f32_bf16(
        const float* __restrict__ in, u16* __restrict__ out, int n4) {
    int i = blockIdx.x * 256 + threadIdx.x;
    if (i >= n4) return;
    float4 v = ((const float4*)in)[i];
    ushort4 o;
    o.x = f2bf(v.x); o.y = f2bf(v.y); o.z = f2bf(v.z); o.w = f2bf(v.w);
    ((ushort4*)out)[i] = o;
}

// ---------------- mask -> additive bias (0 or -1e12) ----------------
__global__ __launch_bounds__(256) void mask_bias(
        const float* __restrict__ m, float* __restrict__ mb, int n) {
    int i = blockIdx.x * 256 + threadIdx.x;
    if (i < n) mb[i] = (m[i] != 0.f) ? 0.f : -1e12f;
}

// ---------------- GEMM: C[m,n] = sum_k A[m,k]*Bt[n,k] + bias[n] ----------------
// 128x128 tile, BK=32, 256 threads (4 waves 2x2, 64x64 each), mfma 16x16x32 bf16.
// MODE 0: bf16 out row-major [M,N]
// MODE 1: bf16 out scattered to Vt[(b*16+h)*64+d][s]
// MODE 2: fp32 out row-major [M,N]
template <int MODE>
__global__ __launch_bounds__(256, 2) void gemm_bt(
        const u16* __restrict__ A, const u16* __restrict__ Bt,
        const float* __restrict__ bias, void* __restrict__ outp,
        int M, int N, int K) {
    __shared__ __align__(16) u16 As[128 * 32];
    __shared__ __align__(16) u16 Bs[128 * 32];
    const int tid = threadIdx.x;
    const int lane = tid & 63;
    const int w = tid >> 6, wm = w >> 1, wn = w & 1;
    const int l15 = lane & 15, l4 = lane >> 4;
    const int m0 = blockIdx.y * 128, n0 = blockIdx.x * 128;

    f32x4 acc[4][4];
#pragma unroll
    for (int i = 0; i < 4; i++)
#pragma unroll
        for (int j = 0; j < 4; j++) acc[i][j] = f32x4{0.f, 0.f, 0.f, 0.f};

    for (int kt = 0; kt < K; kt += 32) {
        __syncthreads();
#pragma unroll
        for (int i = 0; i < 2; i++) {
            int c = tid + i * 256;
            int row = c >> 2, slot = c & 3;
            int cc = slot ^ ((row >> 1) & 3);
            GLL16(A + (size_t)(m0 + row) * K + kt + cc * 8, As + c * 8);
        }
#pragma unroll
        for (int i = 0; i < 2; i++) {
            int c = tid + i * 256;
            int row = c >> 2, slot = c & 3;
            int cc = slot ^ ((row >> 1) & 3);
            GLL16(Bt + (size_t)(n0 + row) * K + kt + cc * 8, Bs + c * 8);
        }
        __syncthreads();

        bf16x8 af[4], bfr[4];
#pragma unroll
        for (int i = 0; i < 4; i++) {
            int row = wm * 64 + i * 16 + l15;
            int slot = l4 ^ ((row >> 1) & 3);
            af[i] = *(const bf16x8*)(As + row * 32 + slot * 8);
        }
#pragma unroll
        for (int j = 0; j < 4; j++) {
            int row = wn * 64 + j * 16 + l15;
            int slot = l4 ^ ((row >> 1) & 3);
            bfr[j] = *(const bf16x8*)(Bs + row * 32 + slot * 8);
        }
#pragma unroll
        for (int i = 0; i < 4; i++)
#pragma unroll
            for (int j = 0; j < 4; j++)
                acc[i][j] = __builtin_amdgcn_mfma_f32_16x16x32_bf16(af[i], bfr[j], acc[i][j], 0, 0, 0);
    }

#pragma unroll
    for (int j = 0; j < 4; j++) {
        int col = n0 + wn * 64 + j * 16 + l15;
        float bv = bias[col];
#pragma unroll
        for (int i = 0; i < 4; i++) {
            int rowb = m0 + wm * 64 + i * 16 + l4 * 4;
            if (MODE == 0) {
                u16* out = (u16*)outp;
#pragma unroll
                for (int r = 0; r < 4; r++)
                    out[(size_t)(rowb + r) * N + col] = f2bf(acc[i][j][r] + bv);
            } else if (MODE == 1) {
                u16* out = (u16*)outp;
                int bb = rowb >> 11, s = rowb & 2047;
                int hh = col >> 6, dd = col & 63;
                ushort4 o;
                o.x = f2bf(acc[i][j][0] + bv);
                o.y = f2bf(acc[i][j][1] + bv);
                o.z = f2bf(acc[i][j][2] + bv);
                o.w = f2bf(acc[i][j][3] + bv);
                *(ushort4*)(out + ((size_t)((bb * 16 + hh) * 64 + dd)) * 2048 + s) = o;
            } else {
                float* out = (float*)outp;
#pragma unroll
                for (int r = 0; r < 4; r++)
                    out[(size_t)(rowb + r) * N + col] = acc[i][j][r] + bv;
            }
        }
    }
}

// ---------------- fused flash attention (swapped-operand, dbuf, base-2 softmax) ----------------
// grid (S/128, B*NH). 256 threads = 4 waves, each wave owns 32 q-rows.
// S^T = mfma(K_frag, Q_frag), O^T = mfma(Vt_frag, P^T_frag).
// K/V double-buffered: STAGE(next) -> compute(cur) -> one __syncthreads per iter.
// Softmax in base-2: s2 = fma(p, scale*log2e (0 if q masked), kbias) then
// clamped to 0 for masked q; defer-max skips rescale when tile max grew < 8.
__global__ __launch_bounds__(256, 3) void attn_fused(
        const u16* __restrict__ Q, const u16* __restrict__ K,
        const u16* __restrict__ Vt, const float* __restrict__ mask,
        const float* __restrict__ mbias, u16* __restrict__ ctx) {
    __shared__ __align__(16) u16 Ks[2][64 * 64];    // [kv][d], swizzled
    __shared__ __align__(16) u16 Vs[2][64 * 64];    // [d][kv], swizzled
    __shared__ __align__(16) u16 Ps[4][32 * 64];    // per-wave P^T as [q][kv], swizzled

    const int tid = threadIdx.x, lane = tid & 63, w = tid >> 6;
    const int l15 = lane & 15, l4 = lane >> 4;
    const int bh = blockIdx.y, b = bh >> 4, h = bh & 15;
    const int qw = blockIdx.x * 128 + w * 32;
    const float SC2 = 0.03125f * 1.44269504088896f;  // (1/sqrt(1024)) * log2(e)
    const float THR2 = 8.0f;

    const u16* Qg = Q + (size_t)b * 2048 * 1024 + h * 64;
    const u16* Kg = K + (size_t)b * 2048 * 1024 + h * 64;
    const u16* Vg = Vt + (size_t)bh * 64 * 2048;
    const float* mp = mask + b * 2048;
    const float* mbp = mbias + b * 2048;

#define STAGE_KV(buf, kvbase) do {                                         \
    _Pragma("unroll")                                                      \
    for (int i_ = 0; i_ < 2; i_++) {                                       \
        int c_ = tid + i_ * 256;                                           \
        int row_ = c_ >> 3, slot_ = c_ & 7;                                \
        int cc_ = slot_ ^ (row_ & 7);                                      \
        GLL16(Kg + (size_t)((kvbase) + row_) * 1024 + cc_ * 8, Ks[buf] + c_ * 8); \
    }                                                                      \
    _Pragma("unroll")                                                      \
    for (int i_ = 0; i_ < 2; i_++) {                                       \
        int c_ = tid + i_ * 256;                                           \
        int row_ = c_ >> 3, slot_ = c_ & 7;                                \
        int cc_ = slot_ ^ (row_ & 7);                                      \
        GLL16(Vg + (size_t)row_ * 2048 + (kvbase) + cc_ * 8, Vs[buf] + c_ * 8); \
    }                                                                      \
} while (0)

    // hoist Q fragments (B-operand layout)
    bf16x8 qfr[2][2];
#pragma unroll
    for (int qi = 0; qi < 2; qi++)
#pragma unroll
        for (int kf = 0; kf < 2; kf++)
            qfr[qi][kf] = *(const bf16x8*)(Qg + (size_t)(qw + qi * 16 + l15) * 1024 + kf * 32 + l4 * 8);

    // q-mask handling, hoisted: masked q => s2 forced to 0 (uniform softmax)
    float mqs[2], qfl[2];
#pragma unroll
    for (int qi = 0; qi < 2; qi++) {
        float mq = mp[qw + qi * 16 + l15];
        mqs[qi] = (mq != 0.f) ? SC2 : 0.f;
        qfl[qi] = (mq != 0.f) ? -__builtin_inff() : 0.f;
    }

    float m_run[2], l_run[2];
    f32x4 oaccT[4][2];   // O^T: [d-frag][q-frag], row=d=l4*4+reg, col=q=l15
#pragma unroll
    for (int qi = 0; qi < 2; qi++) { m_run[qi] = -__builtin_inff(); l_run[qi] = 0.f; }
#pragma unroll
    for (int df = 0; df < 4; df++)
#pragma unroll
        for (int qi = 0; qi < 2; qi++) oaccT[df][qi] = f32x4{0.f, 0.f, 0.f, 0.f};

    STAGE_KV(0, 0);
    __syncthreads();

    for (int it = 0; it < 32; ++it) {
        const int cur = it & 1;
        const int kv0 = it * 64;

        // key-side additive bias for THIS tile — issued before prefetch so the
        // compiler's wait for kb leaves the GLL16s in flight
        float4 kb[4];
#pragma unroll
        for (int kvf = 0; kvf < 4; kvf++)
            kb[kvf] = ((const float4*)(mbp + kv0))[kvf * 4 + l4];

        if (it != 31) STAGE_KV(cur ^ 1, kv0 + 64);

        // ---- S^T = K Q^T ----
        bf16x8 kfr[4][2];
#pragma unroll
        for (int kvf = 0; kvf < 4; kvf++)
#pragma unroll
            for (int kf = 0; kf < 2; kf++) {
                int row = kvf * 16 + l15;
                int slot = (kf * 4 + l4) ^ (row & 7);
                kfr[kvf][kf] = *(const bf16x8*)(Ks[cur] + row * 64 + slot * 8);
            }
        f32x4 p[4][2];
#pragma unroll
        for (int kvf = 0; kvf < 4; kvf++)
#pragma unroll
            for (int qi = 0; qi < 2; qi++) p[kvf][qi] = f32x4{0.f, 0.f, 0.f, 0.f};
        __builtin_amdgcn_s_setprio(1);
#pragma unroll
        for (int kvf = 0; kvf < 4; kvf++)
#pragma unroll
            for (int qi = 0; qi < 2; qi++)
#pragma unroll
                for (int kf = 0; kf < 2; kf++)
                    p[kvf][qi] = __builtin_amdgcn_mfma_f32_16x16x32_bf16(kfr[kvf][kf], qfr[qi][kf], p[kvf][qi], 0, 0, 0);
        __builtin_amdgcn_s_setprio(0);

        // ---- base-2 online softmax ----
        float pm[2];
#pragma unroll
        for (int qi = 0; qi < 2; qi++) {
#pragma unroll
            for (int kvf = 0; kvf < 4; kvf++)
#pragma unroll
                for (int r = 0; r < 4; r++) {
                    float s2 = __builtin_fmaf(p[kvf][qi][r], mqs[qi], kb[kvf][r]);
                    s2 = fmaxf(s2, qfl[qi]);
                    p[kvf][qi][r] = s2;
                }
            float a0 = fmaxf(fmaxf(p[0][qi][0], p[0][qi][1]), fmaxf(p[0][qi][2], p[0][qi][3]));
            float a1 = fmaxf(fmaxf(p[1][qi][0], p[1][qi][1]), fmaxf(p[1][qi][2], p[1][qi][3]));
            float a2 = fmaxf(fmaxf(p[2][qi][0], p[2][qi][1]), fmaxf(p[2][qi][2], p[2][qi][3]));
            float a3 = fmaxf(fmaxf(p[3][qi][0], p[3][qi][1]), fmaxf(p[3][qi][2], p[3][qi][3]));
            float t = fmaxf(fmaxf(a0, a1), fmaxf(a2, a3));
            t = fmaxf(t, __shfl_xor(t, 16));
            t = fmaxf(t, __shfl_xor(t, 32));
            pm[qi] = t;
        }
        // defer-max: skip rescale when tile max grew by < THR2 (base-2 units)
        if (!__all((pm[0] <= m_run[0] + THR2) && (pm[1] <= m_run[1] + THR2))) {
#pragma unroll
            for (int qi = 0; qi < 2; qi++) {
                float mn = fmaxf(m_run[qi], pm[qi]);
                float sc = __builtin_amdgcn_exp2f(m_run[qi] - mn);
                m_run[qi] = mn;
                l_run[qi] *= sc;
#pragma unroll
                for (int df = 0; df < 4; df++) oaccT[df][qi] *= sc;
            }
        }
#pragma unroll
        for (int qi = 0; qi < 2; qi++) {
            float rs = 0.f;
#pragma unroll
            for (int kvf = 0; kvf < 4; kvf++)
#pragma unroll
                for (int r = 0; r < 4; r++) {
                    float ev = __builtin_amdgcn_exp2f(p[kvf][qi][r] - m_run[qi]);
                    p[kvf][qi][r] = ev;
                    rs += ev;
                }
            rs += __shfl_xor(rs, 16);
            rs += __shfl_xor(rs, 32);
            l_run[qi] += rs;
        }

        // ---- P^T -> wave-private LDS (cvt_pk packed b64 writes, swizzled) ----
#pragma unroll
        for (int qi = 0; qi < 2; qi++)
#pragma unroll
            for (int kvf = 0; kvf < 4; kvf++) {
                int q = qi * 16 + l15;
                uint32_t lo = cvtpk(p[kvf][qi][0], p[kvf][qi][1]);
                uint32_t hi = cvtpk(p[kvf][qi][2], p[kvf][qi][3]);
                int s8 = kvf * 2 + (l4 >> 1);
                int off = q * 64 + ((s8 ^ (q & 7)) << 3) + (l4 & 1) * 4;
                *(uint2*)(Ps[w] + off) = uint2{lo, hi};
            }

        // ---- O^T += V^T P^T ----
        bf16x8 vfr[4][2], pb[2][2];
#pragma unroll
        for (int df = 0; df < 4; df++)
#pragma unroll
            for (int kf = 0; kf < 2; kf++) {
                int row = df * 16 + l15;
                int slot = (kf * 4 + l4) ^ (row & 7);
                vfr[df][kf] = *(const bf16x8*)(Vs[cur] + row * 64 + slot * 8);
            }
#pragma unroll
        for (int qi = 0; qi < 2; qi++)
#pragma unroll
            for (int kf = 0; kf < 2; kf++) {
                int q = qi * 16 + l15;
                int s8 = kf * 4 + l4;
                pb[qi][kf] = *(const bf16x8*)(Ps[w] + q * 64 + ((s8 ^ (q & 7)) << 3));
            }
        __builtin_amdgcn_s_setprio(1);
#pragma unroll
        for (int df = 0; df < 4; df++)
#pragma unroll
            for (int qi = 0; qi < 2; qi++)
#pragma unroll
                for (int kf = 0; kf < 2; kf++)
                    oaccT[df][qi] = __builtin_amdgcn_mfma_f32_16x16x32_bf16(vfr[df][kf], pb[qi][kf], oaccT[df][qi], 0, 0, 0);
        __builtin_amdgcn_s_setprio(0);

        __syncthreads();   // drains prefetch vmcnt + makes next buffer safe
    }

    // ---- epilogue: ctx[token][h*64+d] = O^T / l ----
#pragma unroll
    for (int qi = 0; qi < 2; qi++) {
        float rl = 1.0f / l_run[qi];
        int tok = qw + qi * 16 + l15;
#pragma unroll
        for (int df = 0; df < 4; df++) {
            uint2 o;
            o.x = cvtpk(oaccT[df][qi][0] * rl, oaccT[df][qi][1] * rl);
            o.y = cvtpk(oaccT[df][qi][2] * rl, oaccT[df][qi][3] * rl);
            *(uint2*)(ctx + (size_t)(b * 2048 + tok) * 1024 + h * 64 + df * 16 + l4 * 4) = o;
        }
    }
#undef STAGE_KV
}

extern "C" void kernel_launch(void* const* d_in, const int* in_sizes, int n_in,
                              void* d_out, int out_size, void* d_ws, size_t ws_size,
                              hipStream_t stream) {
    const float* hs    = (const float*)d_in[0];
    const float* masks = (const float*)d_in[1];
    const float* Wq = (const float*)d_in[2];
    const float* bq = (const float*)d_in[3];
    const float* Wk = (const float*)d_in[4];
    const float* bk = (const float*)d_in[5];
    const float* Wv = (const float*)d_in[6];
    const float* bv = (const float*)d_in[7];
    const float* Wo = (const float*)d_in[8];
    const float* bo = (const float*)d_in[9];

    const int NT = 4 * 2048;   // 8192 tokens
    const int H = 1024;

    u16* hs_b = (u16*)d_ws;
    u16* wq_b = hs_b + (size_t)NT * H;
    u16* wk_b = wq_b + (size_t)H * H;
    u16* wv_b = wk_b + (size_t)H * H;
    u16* wo_b = wv_b + (size_t)H * H;
    u16* Qb   = wo_b + (size_t)H * H;
    u16* Kb   = Qb + (size_t)NT * H;
    u16* Vtb  = Kb + (size_t)NT * H;
    u16* Cb   = hs_b;
    // mask-bias overlays wq_b's region (dead after the Q GEMM)
    float* mb = (float*)wq_b;

    cvt_f32_bf16<<<NT * H / 1024, 256, 0, stream>>>(hs, hs_b, NT * H / 4);
    cvt_f32_bf16<<<H * H / 1024, 256, 0, stream>>>(Wq, wq_b, H * H / 4);
    cvt_f32_bf16<<<H * H / 1024, 256, 0, stream>>>(Wk, wk_b, H * H / 4);
    cvt_f32_bf16<<<H * H / 1024, 256, 0, stream>>>(Wv, wv_b, H * H / 4);
    cvt_f32_bf16<<<H * H / 1024, 256, 0, stream>>>(Wo, wo_b, H * H / 4);

    dim3 gg(H / 128, NT / 128);   // (8, 64)
    gemm_bt<0><<<gg, 256, 0, stream>>>(hs_b, wq_b, bq, Qb,  NT, H, H);
    gemm_bt<0><<<gg, 256, 0, stream>>>(hs_b, wk_b, bk, Kb,  NT, H, H);
    gemm_bt<1><<<gg, 256, 0, stream>>>(hs_b, wv_b, bv, Vtb, NT, H, H);

    mask_bias<<<(4 * 2048 + 255) / 256, 256, 0, stream>>>(masks, mb, 4 * 2048);

    attn_fused<<<dim3(2048 / 128, 64), 256, 0, stream>>>(Qb, Kb, Vtb, masks, mb, Cb);

    gemm_bt<2><<<gg, 256, 0, stream>>>(Cb, wo_b, bo, d_out, NT, H, H);
}